// Round 6
// baseline (50.557 us; speedup 1.0000x reference)
//
#include <hip/hip_runtime.h>

// LDDMM variational evolve: N-body Gaussian kernel sums, N=8192, D=3, fp32.
// dmom_i = (1/SIG2) * sum_j K_ij * <mom_i,mom_j> * (pos_i - pos_j)
// dpos_i = sum_j K_ij * mom_j
// K_ij = exp(-||pos_i-pos_j||^2/(2*SIG2)), SIG2=0.01 -> exp2(-72.1348*d2)
//
// d2 = ri + rj - 2<xi,xj>. Accumulate S=sum(s), SP=sum(s*xj_scaled) so
// dmom_i = 100*(xi*S - SP/A_DOT).
// exp = __builtin_amdgcn_exp2f (plain exp2f -> OCML fixup; R2 measured flat).
// R3-R5 evidence: 16w/CU and 8w/CU both ~68 SIMD-cyc/wave-eval -> shared
// throughput wall, not latency. R6: j-data is WAVE-UNIFORM -> no LDS at all;
// prep kernel packs {A_DOT*x, A_DOT*y, A_DOT*z, A_R*r2, mx,my,mz,0} per j,
// main loop does 2 uniform float4 loads/j (scalarizable to s_load).

#define NPTS    8192
#define THREADS 256
#define ILANES  4
#define IBLK    (THREADS * ILANES)   // 1024 i's per block
#define NJC     64
#define JBLK    (NPTS / NJC)         // 128 j's per block

#define A_DOT 144.269504088896f      // 2*50*log2(e)
#define A_R   (-72.134752044448f)    // -50*log2(e)
#define INV_SIG2 100.0f

#define EXP2(x) __builtin_amdgcn_exp2f(x)

__global__ __launch_bounds__(256)
void lddmm_prep(const float* __restrict__ mom, const float* __restrict__ pos,
                float* __restrict__ pm)
{
    const int j = blockIdx.x * 256 + threadIdx.x;   // 32 blocks x 256 = 8192
    const float x = pos[3*j+0], y = pos[3*j+1], z = pos[3*j+2];
    const float r2 = x*x + y*y + z*z;
    float4* v = reinterpret_cast<float4*>(pm + (size_t)8 * j);
    v[0] = make_float4(A_DOT*x, A_DOT*y, A_DOT*z, A_R*r2);
    v[1] = make_float4(mom[3*j+0], mom[3*j+1], mom[3*j+2], 0.0f);
}

template <bool ATOMIC>
__global__ __launch_bounds__(THREADS, 2)
void lddmm_main(const float* __restrict__ mom,
                const float* __restrict__ pos,
                const float* __restrict__ pm,      // packed j-records, 8 floats/j
                float* __restrict__ partial,       // [NJC][6][NPTS] when !ATOMIC
                float* __restrict__ out)           // used when ATOMIC
{
    const int t  = threadIdx.x;
    const int i0 = blockIdx.x * IBLK;
    const int jc = blockIdx.y;

    // Per-i registers (fully unrolled -> static indexing, stays in VGPRs)
    float xi[ILANES], yi[ILANES], zi[ILANES], pxi[ILANES], pyi[ILANES], pzi[ILANES], ci[ILANES];
    float S[ILANES], SPx[ILANES], SPy[ILANES], SPz[ILANES], apx[ILANES], apy[ILANES], apz[ILANES];
    #pragma unroll
    for (int k = 0; k < ILANES; ++k) {
        const int i = i0 + k * THREADS + t;
        xi[k] = pos[3*i+0]; yi[k] = pos[3*i+1]; zi[k] = pos[3*i+2];
        pxi[k] = mom[3*i+0]; pyi[k] = mom[3*i+1]; pzi[k] = mom[3*i+2];
        ci[k] = A_R * (xi[k]*xi[k] + yi[k]*yi[k] + zi[k]*zi[k]);
        S[k]=0.f; SPx[k]=0.f; SPy[k]=0.f; SPz[k]=0.f; apx[k]=0.f; apy[k]=0.f; apz[k]=0.f;
    }

    // Wave-uniform j-stream for this block's chunk.
    const float4* __restrict__ pmv =
        reinterpret_cast<const float4*>(pm) + (size_t)2 * jc * JBLK;

    #pragma unroll 4
    for (int j = 0; j < JBLK; ++j) {
        const float4 P = pmv[2*j+0];   // uniform address -> s_load / broadcast
        const float4 M = pmv[2*j+1];
        #pragma unroll
        for (int k = 0; k < ILANES; ++k) {
            float arg = __builtin_fmaf(xi[k], P.x, ci[k] + P.w);
            arg = __builtin_fmaf(yi[k], P.y, arg);
            arg = __builtin_fmaf(zi[k], P.z, arg);
            const float K = EXP2(arg);
            const float C = __builtin_fmaf(pzi[k], M.z,
                              __builtin_fmaf(pyi[k], M.y, pxi[k]*M.x));
            const float s = K * C;
            S[k]  += s;
            SPx[k] = __builtin_fmaf(s, P.x, SPx[k]);
            SPy[k] = __builtin_fmaf(s, P.y, SPy[k]);
            SPz[k] = __builtin_fmaf(s, P.z, SPz[k]);
            apx[k] = __builtin_fmaf(K, M.x, apx[k]);
            apy[k] = __builtin_fmaf(K, M.y, apy[k]);
            apz[k] = __builtin_fmaf(K, M.z, apz[k]);
        }
    }

    const float US = INV_SIG2 / A_DOT;
    #pragma unroll
    for (int k = 0; k < ILANES; ++k) {
        const int i = i0 + k * THREADS + t;
        const float amx = INV_SIG2*xi[k]*S[k] - US*SPx[k];
        const float amy = INV_SIG2*yi[k]*S[k] - US*SPy[k];
        const float amz = INV_SIG2*zi[k]*S[k] - US*SPz[k];
        if (!ATOMIC) {
            float* base = partial + (size_t)jc * (6 * NPTS);
            base[0*NPTS + i] = amx;
            base[1*NPTS + i] = amy;
            base[2*NPTS + i] = amz;
            base[3*NPTS + i] = apx[k];
            base[4*NPTS + i] = apy[k];
            base[5*NPTS + i] = apz[k];
        } else {
            atomicAdd(&out[3*i+0], amx);
            atomicAdd(&out[3*i+1], amy);
            atomicAdd(&out[3*i+2], amz);
            atomicAdd(&out[3*NPTS + 3*i+0], apx[k]);
            atomicAdd(&out[3*NPTS + 3*i+1], apy[k]);
            atomicAdd(&out[3*NPTS + 3*i+2], apz[k]);
        }
    }
}

// Reduce: one output scalar per thread, 192 blocks. Adjacent threads ->
// adjacent i within a comp-plane -> coalesced loads (stride 6*NPTS between
// jc-planes). 64 independent loads per thread.
__global__ __launch_bounds__(256)
void lddmm_reduce(const float* __restrict__ partial, float* __restrict__ out)
{
    const int idx = blockIdx.x * 256 + threadIdx.x;   // 0 .. 6*NPTS-1
    float s = 0.0f;
    #pragma unroll 8
    for (int jc = 0; jc < NJC; ++jc)
        s += partial[(size_t)jc * (6 * NPTS) + idx];
    const int comp = idx >> 13;          // / NPTS
    const int i    = idx & (NPTS - 1);
    const int base = (comp < 3) ? 0 : 3 * NPTS;
    const int c    = (comp < 3) ? comp : comp - 3;
    out[base + 3 * i + c] = s;
}

extern "C" void kernel_launch(void* const* d_in, const int* in_sizes, int n_in,
                              void* d_out, int out_size, void* d_ws, size_t ws_size,
                              hipStream_t stream)
{
    const float* mom = (const float*)d_in[0];
    const float* pos = (const float*)d_in[1];
    float* out = (float*)d_out;

    float* pm      = (float*)d_ws;                       // 8192*8*4 = 256 KB
    float* partial = (float*)d_ws + (size_t)8 * NPTS;    // NJC*6*NPTS*4 = 12.6 MB

    const size_t need = ((size_t)8 * NPTS + (size_t)NJC * 6 * NPTS) * sizeof(float);
    dim3 grid(NPTS / IBLK, NJC);                         // 8 x 64 = 512 blocks

    if (ws_size >= need) {
        lddmm_prep<<<NPTS / 256, 256, 0, stream>>>(mom, pos, pm);
        lddmm_main<false><<<grid, THREADS, 0, stream>>>(mom, pos, pm, partial, out);
        lddmm_reduce<<<(6 * NPTS) / 256, 256, 0, stream>>>(partial, out);
    } else if (ws_size >= (size_t)8 * NPTS * sizeof(float)) {
        hipMemsetAsync(out, 0, (size_t)6 * NPTS * sizeof(float), stream);
        lddmm_prep<<<NPTS / 256, 256, 0, stream>>>(mom, pos, pm);
        lddmm_main<true><<<grid, THREADS, 0, stream>>>(mom, pos, pm, nullptr, out);
    }
}